// Round 3
// baseline (1268.495 us; speedup 1.0000x reference)
//
#include <hip/hip_runtime.h>
#include <hip/hip_bf16.h>

typedef unsigned int u32;
typedef unsigned long long u64;

// ---------------- workspace layout (bytes) ----------------
// conv phase: y + wT (wT aliases everything below, dead after k_conv1)
#define OFF_Y      0ull             // 8,388,608
#define OFF_WT     8388608ull       // 9,437,184 -> end 17,825,792
// post-conv phase (aliases wT region):
#define OFF_ZPART  8388608ull       // 4*45*4096*4 = 2,949,120
#define OFF_SCORES 11337728ull      // 147,456
#define OFF_DRAW   11485184ull      // 589,824
#define OFF_HIST   12075008ull      // 524,288
#define OFF_SEL    12599296ull      // 256
#define OFF_CNT    12599552ull      // 256
#define OFF_CAND   12599808ull      // 65,536
#define MEMSET_LEN (524288ull + 256ull + 256ull + 65536ull)   // hist..cand
#define OFF_TOPV   12665344ull      // 24,576
#define OFF_TOPI   12689920ull      // 24,576
#define OFF_BOXES  12714496ull      // 98,304
#define OFF_VW     12812800ull      // 1,024
#define OFF_MASK   12813824ull      // 4,608,000 -> 17,421,824
#define OFF_KEEP   17421824ull      // 2,048
#define OFF_KC     17423872ull      // 256
#define OFF_KW     17424128ull      // 1,024

#define NS     36864
#define PRE    6000
#define POST   300
#define SORTN  8192
#define MROW   96   // mask words per row (94 used)

// ================= K0: weight transpose gw[co][ci][k] -> wT[ci][co][k] ======
__global__ __launch_bounds__(256) void k_wtrans(const float* __restrict__ gw,
                                                float* __restrict__ wT) {
    int o = blockIdx.x * 256 + threadIdx.x;   // output index, coalesced write
    if (o >= 512 * 512 * 9) return;
    int ci = o / 4608;
    int r = o - ci * 4608;
    int co = r / 9;
    int k = r - co * 9;
    wT[o] = gw[(co * 512 + ci) * 9 + k];
}

// ================= K1: 3x3 conv 512->512 + bias + relu (v3) =================
// grid 256 = 16 co-blocks x 16 h-blocks; block 256 thr = 4 waves.
// wave w: co octet co_base..+7, rows h0..h0+3, lane = col.
// weights: VMEM broadcast loads from wT (vmcnt, reg-double-buffered).
// x: LDS double-buffered 16-ci chunks, taps reg-double-buffered (lgkmcnt).
#define CI 16
#define XROW 68
#define CHUNK_ELEMS (CI * 6 * XROW)   // 6528
__global__ __launch_bounds__(256, 1) void k_conv1(const float* __restrict__ x,
                                                  const float* __restrict__ wT,
                                                  const float* __restrict__ gb,
                                                  float* __restrict__ y) {
    __shared__ float xs[2][CHUNK_ELEMS];   // 2 x 26,112 B
    const int t = threadIdx.x;
    const int tx = t & 63;
    const int wvid = __builtin_amdgcn_readfirstlane(t >> 6);
    const int cob = (blockIdx.x & 15) << 5;
    const int h0 = (blockIdx.x >> 4) << 2;
    const int co_base = cob + (wvid << 3);

    // ---- precompute staging map (same for every chunk; only ci-base shifts)
    int offs[26];
    u32 vmask = 0;
#pragma unroll
    for (int u = 0; u < 26; ++u) {
        int idx = t + u * 256;
        offs[u] = 0;
        if (idx < CHUNK_ELEMS) {
            int ci = idx / (6 * XROW);
            int rem = idx - ci * (6 * XROW);
            int row = rem / XROW;
            int slot = rem - row * XROW;
            int gr = h0 + row - 1, gc = slot - 1;
            if ((unsigned)gr < 64u && (unsigned)gc < 64u) {
                offs[u] = ci * 4096 + (gr << 6) + gc;
                vmask |= (1u << u);
            }
        }
    }

    float acc[8][4];
#pragma unroll
    for (int c = 0; c < 8; ++c)
#pragma unroll
        for (int r = 0; r < 4; ++r) acc[c][r] = 0.f;

    float st[26];
    // ---- prologue: stage chunk 0
#pragma unroll
    for (int u = 0; u < 26; ++u)
        st[u] = (vmask >> u & 1) ? x[offs[u]] : 0.f;
#pragma unroll
    for (int u = 0; u < 26; ++u) {
        int idx = t + u * 256;
        if (idx < CHUNK_ELEMS) xs[0][idx] = st[u];
    }
    __syncthreads();

    float4 wa[18], wb[18];
    float xa[18], xb[18];
    {
        const float4* p = (const float4*)(wT + ((size_t)0 * 512 + co_base) * 9);
#pragma unroll
        for (int i = 0; i < 18; ++i) wa[i] = p[i];
        const float* xbse = &xs[0][tx];
#pragma unroll
        for (int r = 0; r < 6; ++r) {
            xa[r * 3 + 0] = xbse[r * XROW + 0];
            xa[r * 3 + 1] = xbse[r * XROW + 1];
            xa[r * 3 + 2] = xbse[r * XROW + 2];
        }
    }

    int p = 0;
#pragma unroll 1
    for (int cc = 0; cc < 32; ++cc) {
        // issue global loads for next chunk (consumed at chunk end)
        const int ccn = (cc + 1 < 32) ? cc + 1 : 31;
        const float* xsrc = x + ccn * CI * 4096;
#pragma unroll
        for (int u = 0; u < 26; ++u)
            st[u] = (vmask >> u & 1) ? xsrc[offs[u]] : 0.f;

        const float* B = xs[p];
#pragma unroll 1
        for (int ci = 0; ci < CI; ci += 2) {
            const int gci = cc * CI + ci;
            // prefetch ci+1 -> b
            {
                int g1 = gci + 1 < 512 ? gci + 1 : 511;
                const float4* wp = (const float4*)(wT + ((size_t)g1 * 512 + co_base) * 9);
#pragma unroll
                for (int i = 0; i < 18; ++i) wb[i] = wp[i];
                const float* xp = B + (ci + 1) * (6 * XROW) + tx;
#pragma unroll
                for (int r = 0; r < 6; ++r) {
                    xb[r * 3 + 0] = xp[r * XROW + 0];
                    xb[r * 3 + 1] = xp[r * XROW + 1];
                    xb[r * 3 + 2] = xp[r * XROW + 2];
                }
            }
            // FMA on a
            {
                const float* w = (const float*)wa;
#pragma unroll
                for (int co = 0; co < 8; ++co)
#pragma unroll
                    for (int k = 0; k < 9; ++k) {
                        const int kh = k / 3, kw = k - kh * 3;
                        float wv_ = w[co * 9 + k];
#pragma unroll
                        for (int r = 0; r < 4; ++r)
                            acc[co][r] += wv_ * xa[(r + kh) * 3 + kw];
                    }
            }
            // prefetch ci+2 -> a (x only if within chunk)
            {
                int g2 = gci + 2 < 512 ? gci + 2 : 511;
                const float4* wp = (const float4*)(wT + ((size_t)g2 * 512 + co_base) * 9);
#pragma unroll
                for (int i = 0; i < 18; ++i) wa[i] = wp[i];
                if (ci + 2 < CI) {
                    const float* xp = B + (ci + 2) * (6 * XROW) + tx;
#pragma unroll
                    for (int r = 0; r < 6; ++r) {
                        xa[r * 3 + 0] = xp[r * XROW + 0];
                        xa[r * 3 + 1] = xp[r * XROW + 1];
                        xa[r * 3 + 2] = xp[r * XROW + 2];
                    }
                }
            }
            // FMA on b
            {
                const float* w = (const float*)wb;
#pragma unroll
                for (int co = 0; co < 8; ++co)
#pragma unroll
                    for (int k = 0; k < 9; ++k) {
                        const int kh = k / 3, kw = k - kh * 3;
                        float wv_ = w[co * 9 + k];
#pragma unroll
                        for (int r = 0; r < 4; ++r)
                            acc[co][r] += wv_ * xb[(r + kh) * 3 + kw];
                    }
            }
        }
        __syncthreads();   // all reads of buffer p complete
#pragma unroll
        for (int u = 0; u < 26; ++u) {
            int idx = t + u * 256;
            if (idx < CHUNK_ELEMS) xs[p ^ 1][idx] = st[u];
        }
        __syncthreads();
        p ^= 1;
        // reload x taps for ci=0 of new chunk
        {
            const float* xp = &xs[p][tx];
#pragma unroll
            for (int r = 0; r < 6; ++r) {
                xa[r * 3 + 0] = xp[r * XROW + 0];
                xa[r * 3 + 1] = xp[r * XROW + 1];
                xa[r * 3 + 2] = xp[r * XROW + 2];
            }
        }
    }

#pragma unroll
    for (int co = 0; co < 8; ++co) {
        float bias = gb[co_base + co];
#pragma unroll
        for (int r = 0; r < 4; ++r) {
            float v = acc[co][r] + bias;
            v = v > 0.f ? v : 0.f;
            y[(co_base + co) * 4096 + ((h0 + r) << 6) + tx] = v;
        }
    }
}

// ================= K2a: 1x1 heads, partial over ci quarters =================
// grid 256 = 64 px-chunks x 4 ci-quarters; block 256 = 64 px x 4 wave-groups
__global__ __launch_bounds__(256) void k_heads_part(const float* __restrict__ y,
                                                    const float* __restrict__ cw,
                                                    const float* __restrict__ bw,
                                                    float* __restrict__ zpart) {
    __shared__ float ys[128 * 64];  // 32 KB
    const int t = threadIdx.x;
    const int px = t & 63;
    const int gu = __builtin_amdgcn_readfirstlane(t >> 6);
    const int px0 = (blockIdx.x & 63) << 6;
    const int q = blockIdx.x >> 6;
    const int cib = q << 7;
    const int nch = (gu == 0) ? 12 : 11;

    const float* wrow[12];
#pragma unroll
    for (int j = 0; j < 12; ++j) {
        int ch = gu + 4 * j;
        if (ch < 9) wrow[j] = cw + ch * 512;
        else if (ch < 45) wrow[j] = bw + (ch - 9) * 512;
        else wrow[j] = cw;
    }
    float acc[12];
#pragma unroll
    for (int j = 0; j < 12; ++j) acc[j] = 0.f;

    for (int idx = t; idx < 128 * 64; idx += 256) {
        int ci = idx >> 6;
        int pp = idx & 63;
        ys[idx] = y[(cib + ci) * 4096 + px0 + pp];
    }
    __syncthreads();
    for (int ci = 0; ci < 128; ++ci) {
        float v = ys[ci * 64 + px];
        int cig = cib + ci;
#pragma unroll
        for (int j = 0; j < 12; ++j)
            if (j < nch) acc[j] += v * wrow[j][cig];
    }
    for (int j = 0; j < nch; ++j) {
        int ch = gu + 4 * j;
        zpart[((q * 45 + ch) << 12) + px0 + px] = acc[j];
    }
}

// ================= K2b: reduce partials + bias + sigmoid + hist =============
__global__ __launch_bounds__(256) void k_hreduce(const float* __restrict__ zpart,
                                                 const float* __restrict__ cb,
                                                 const float* __restrict__ bb,
                                                 float* __restrict__ scores,
                                                 float* __restrict__ draw,
                                                 u32* __restrict__ hist) {
    int i = blockIdx.x * 256 + threadIdx.x;
    if (i >= 45 * 4096) return;
    int ch = i >> 12;
    int sp = i & 4095;
    float z = zpart[((0 * 45 + ch) << 12) + sp] + zpart[((1 * 45 + ch) << 12) + sp] +
              zpart[((2 * 45 + ch) << 12) + sp] + zpart[((3 * 45 + ch) << 12) + sp];
    if (ch < 9) {
        z += cb[ch];
        float s = 1.f / (1.f + expf(-z));
        scores[(ch << 12) + sp] = s;
        u32 sb = __float_as_uint(s);
        atomicAdd(&hist[sb >> 13], 1u);
    } else {
        z += bb[ch - 9];
        draw[((ch - 9) << 12) + sp] = z;
    }
}

// ================= K3: find boundary bin (rank 6000 from top), parallel =====
__global__ __launch_bounds__(1024) void k_scan_hist(const u32* __restrict__ hist,
                                                    int* __restrict__ sel) {
    __shared__ u32 csum[1024];
    __shared__ u32 suf[1024];
    int t = threadIdx.x;
    u32 s = 0;
    const u32* hp = hist + t * 128;
    for (int i = 0; i < 128; ++i) s += hp[i];
    csum[t] = s;
    suf[t] = s;
    __syncthreads();
    for (int off = 1; off < 1024; off <<= 1) {
        u32 v = suf[t] + ((t + off < 1024) ? suf[t + off] : 0u);
        __syncthreads();
        suf[t] = v;
        __syncthreads();
    }
    u32 above = suf[t] - csum[t];               // sum of chunks strictly above t
    if (above < (u32)PRE && suf[t] >= (u32)PRE) {
        u32 run = above;
        int bstar = t * 128;
        u32 found = 0;
#pragma unroll 8
        for (int bb2 = 127; bb2 >= 0; --bb2) {
            u32 c = hp[bb2];
            if (!found && run + c >= (u32)PRE) { bstar = t * 128 + bb2; found = 1; }
            if (!found) run += c;
        }
        sel[0] = bstar;
    }
}

// ================= K4: compact candidates (bin >= bstar) =================
__global__ __launch_bounds__(256) void k_compact(const float* __restrict__ scores,
                                                 const int* __restrict__ sel,
                                                 u64* __restrict__ cand,
                                                 int* __restrict__ cnt) {
    int i = blockIdx.x * 256 + threadIdx.x;
    if (i >= NS) return;
    u32 sb = __float_as_uint(scores[i]);
    if ((int)(sb >> 13) >= sel[0]) {
        int pos = atomicAdd(cnt, 1);
        if (pos < SORTN) cand[pos] = ((u64)sb << 32) | (u32)(~i);
    }
}

// ================= K5: bitonic sort 8192 keys (descending) =================
// j<=4 stages done in registers (each thread owns 8 contiguous elements)
__global__ __launch_bounds__(1024) void k_sort(const u64* __restrict__ cand,
                                               float* __restrict__ topv,
                                               int* __restrict__ topi) {
    __shared__ u64 sk[SORTN];  // 64 KB
    const int t = threadIdx.x;
    for (int i = t; i < SORTN; i += 1024) sk[i] = cand[i];
    __syncthreads();

    const int base = t << 3;
    u64 a[8];
    // ---- phases k=2,4,8 entirely in registers
    {
#pragma unroll
        for (int u = 0; u < 8; ++u) a[u] = sk[base + u];
#pragma unroll
        for (int k = 2; k <= 8; k <<= 1) {
#pragma unroll
            for (int j = k >> 1; j > 0; j >>= 1) {
#pragma unroll
                for (int u = 0; u < 8; ++u) {
                    if ((u & j) == 0) {
                        int l = u | j;
                        bool up = (((base + u) & k) == 0);
                        u64 x0 = a[u], x1 = a[l];
                        if (up ? (x0 < x1) : (x0 > x1)) { a[u] = x1; a[l] = x0; }
                    }
                }
            }
        }
#pragma unroll
        for (int u = 0; u < 8; ++u) sk[base + u] = a[u];
        __syncthreads();
    }
    // ---- phases k=16..8192
    for (int k = 16; k <= SORTN; k <<= 1) {
        for (int j = k >> 1; j >= 8; j >>= 1) {
#pragma unroll
            for (int s = 0; s < 4; ++s) {
                int pidx = t + (s << 10);
                int i = ((pidx & ~(j - 1)) << 1) | (pidx & (j - 1));
                int l = i | j;
                u64 x0 = sk[i], x1 = sk[l];
                bool up = ((i & k) == 0);
                if (up ? (x0 < x1) : (x0 > x1)) { sk[i] = x1; sk[l] = x0; }
            }
            __syncthreads();
        }
        // j = 4,2,1 in registers
#pragma unroll
        for (int u = 0; u < 8; ++u) a[u] = sk[base + u];
        {
            bool up = ((base & k) == 0);   // uniform across the 8 (k>=16)
#pragma unroll
            for (int j = 4; j > 0; j >>= 1) {
#pragma unroll
                for (int u = 0; u < 8; ++u) {
                    if ((u & j) == 0) {
                        int l = u | j;
                        u64 x0 = a[u], x1 = a[l];
                        if (up ? (x0 < x1) : (x0 > x1)) { a[u] = x1; a[l] = x0; }
                    }
                }
            }
        }
#pragma unroll
        for (int u = 0; u < 8; ++u) sk[base + u] = a[u];
        __syncthreads();
    }

    for (int r = t; r < PRE; r += 1024) {
        u64 key = sk[r];
        topv[r] = __uint_as_float((u32)(key >> 32));
        topi[r] = (int)(~(u32)key);
    }
}

// ================= K6: decode + clip + valid bitmask =================
__global__ __launch_bounds__(256) void k_decode(const float* __restrict__ draw,
                                                const float* __restrict__ anchors,
                                                const int* __restrict__ ishape,
                                                const int* __restrict__ topi,
                                                float* __restrict__ boxes,
                                                u64* __restrict__ vw) {
    int r = blockIdx.x * 256 + threadIdx.x;
    bool valid = false;
    if (r < PRE) {
        int i = topi[r];
        int c = i >> 10;
        int t4 = i & 1023;
        int base = c * 4096 + (t4 << 2);
        float dx = draw[base], dy = draw[base + 1];
        float dw = draw[base + 2], dh = draw[base + 3];
        const float* a = anchors + i * 4;
        float aw = a[2] - a[0], ah = a[3] - a[1];
        float ax = a[0] + 0.5f * aw, ay = a[1] + 0.5f * ah;
        const float CLIPV = (float)4.135166556742356;
        dw = fminf(dw, CLIPV);
        dh = fminf(dh, CLIPV);
        float px = dx * aw + ax, py = dy * ah + ay;
        float pw = expf(dw) * aw, ph = expf(dh) * ah;
        float wimg = (float)ishape[1], himg = (float)ishape[0];
        float x1 = fminf(fmaxf(px - 0.5f * pw, 0.f), wimg);
        float y1 = fminf(fmaxf(py - 0.5f * ph, 0.f), himg);
        float x2 = fminf(fmaxf(px + 0.5f * pw, 0.f), wimg);
        float y2 = fminf(fmaxf(py + 0.5f * ph, 0.f), himg);
        valid = (x2 - x1 >= 16.f) && (y2 - y1 >= 16.f);
        *(float4*)(boxes + r * 4) = make_float4(x1, y1, x2, y2);
    }
    u64 bm = __ballot(valid);
    if ((threadIdx.x & 63) == 0) vw[r >> 6] = bm;
}

// ================= K7: suppression bitmask (iou > 0.7, j > row) =============
__global__ __launch_bounds__(256) void k_mask(const float* __restrict__ boxes,
                                              u64* __restrict__ mask) {
    __shared__ float4 cbx[16 * 65];
    const int t = threadIdx.x;
    const int r0 = blockIdx.x << 4;
    const int row = r0 + (t >> 4);
    const int wloc = t & 15;
    float4 rb = *(const float4*)(boxes + row * 4);
    float area_a = (rb.z - rb.x) * (rb.w - rb.y);
    for (int chunk = 0; chunk < 6; ++chunk) {
        int j0c = chunk << 10;
        for (int idx = t; idx < 1024; idx += 256) {
            int j = j0c + idx;
            float4 v = make_float4(0.f, 0.f, 0.f, 0.f);
            if (j < PRE) v = *(const float4*)(boxes + j * 4);
            cbx[(idx >> 6) * 65 + (idx & 63)] = v;
        }
        __syncthreads();
        u64 bits = 0;
        const float4* cbr = cbx + wloc * 65;
        for (int b = 0; b < 64; ++b) {
            int j = j0c + (wloc << 6) + b;
            float4 ob = cbr[b];
            float area_b = (ob.z - ob.x) * (ob.w - ob.y);
            float ltx = fmaxf(rb.x, ob.x), lty = fmaxf(rb.y, ob.y);
            float rbx = fminf(rb.z, ob.z), rby = fminf(rb.w, ob.w);
            float wx = fmaxf(rbx - ltx, 0.f), wy = fmaxf(rby - lty, 0.f);
            float inter = wx * wy;
            float uni = area_a + area_b - inter;
            float iou = (uni > 0.f) ? (inter / uni) : 0.f;
            if (iou > 0.7f && j > row && j < PRE) bits |= (1ull << b);
        }
        mask[(size_t)row * MROW + (chunk << 4) + wloc] = bits;
        __syncthreads();
    }
}

// ================= K8: serial greedy NMS, batch-16 LDS row prefetch =========
__global__ __launch_bounds__(64) void k_nms(const u64* __restrict__ mask,
                                            const u64* __restrict__ vw,
                                            int* __restrict__ keeplist,
                                            int* __restrict__ kc_out,
                                            u64* __restrict__ kw_out) {
    __shared__ u64 rem[MROW];
    __shared__ u64 rows16[16][MROW];   // 12,288 B
    const int lane = threadIdx.x;
    for (int qd = lane; qd < MROW; qd += 64) rem[qd] = 0ull;
    __syncthreads();
    int kc = 0;
    bool done = false;
    for (int w = 0; w < 94 && !done; ++w) {
        u64 aw = vw[w] & ~rem[w];
        u64 kwbits = 0;
        while (aw != 0ull && !done) {
            // extract up to 16 lowest set bits (uniform across lanes)
            int bq[16];
            u64 tmp = aw;
#pragma unroll
            for (int q2 = 0; q2 < 16; ++q2) {
                bq[q2] = tmp ? __builtin_ctzll(tmp) : 64;
                tmp &= tmp - 1;
            }
            // cooperative prefetch of those rows into LDS
#pragma unroll
            for (int u = 0; u < 24; ++u) {
                int i = lane + u * 64;
                int q2 = i / MROW;
                int ww = i - q2 * MROW;
                if (bq[q2] < 64)
                    rows16[q2][ww] = mask[(size_t)((w << 6) + bq[q2]) * MROW + ww];
            }
            __syncthreads();
            // serial resolve
            for (int q2 = 0; q2 < 16; ++q2) {
                int b = bq[q2];
                if (b >= 64) break;
                if (!((aw >> b) & 1ull)) continue;   // suppressed within batch
                if (lane == 0) keeplist[kc] = (w << 6) + b;
                kc++;
                kwbits |= (1ull << b);
                if (kc >= POST) { done = true; break; }
                rem[lane] |= rows16[q2][lane];
                if (lane < MROW - 64) rem[64 + lane] |= rows16[q2][64 + lane];
                aw &= ~rows16[q2][w];
                aw &= ~(1ull << b);
            }
            __syncthreads();
        }
        if (lane == 0) kw_out[w] = kwbits;
        __syncthreads();
    }
    if (lane == 0) *kc_out = kc;
}

// ================= K9: write 300 boxes + scores =================
__global__ __launch_bounds__(384) void k_out(const float* __restrict__ boxes,
                                             const float* __restrict__ topv,
                                             const int* __restrict__ keeplist,
                                             const int* __restrict__ kc_p,
                                             const u64* __restrict__ kw,
                                             float* __restrict__ out) {
    int j = threadIdx.x;
    if (j >= POST) return;
    int kc = *kc_p;
    int r;
    float sc;
    if (j < kc) {
        r = keeplist[j];
        sc = topv[r];
    } else {
        int target = j - kc;
        r = PRE - 1;
        int cum = 0;
        for (int w = 0; w < 94; ++w) {
            u64 kb = kw[w];
            int nvalid = (w < 93) ? 64 : 48;
            u64 vmask2 = (nvalid == 64) ? ~0ull : ((1ull << nvalid) - 1ull);
            u64 nk = (~kb) & vmask2;
            int c = __popcll(nk);
            if (cum + c > target) {
                int need = target - cum;
                u64 m = nk;
                for (int q = 0; q < need; ++q) m &= (m - 1);
                r = (w << 6) + __builtin_ctzll(m);
                break;
            }
            cum += c;
        }
        sc = -1.0f;
    }
    out[j * 4 + 0] = boxes[r * 4 + 0];
    out[j * 4 + 1] = boxes[r * 4 + 1];
    out[j * 4 + 2] = boxes[r * 4 + 2];
    out[j * 4 + 3] = boxes[r * 4 + 3];
    out[1200 + j] = sc;
}

extern "C" void kernel_launch(void* const* d_in, const int* in_sizes, int n_in,
                              void* d_out, int out_size, void* d_ws, size_t ws_size,
                              hipStream_t stream) {
    const float* x = (const float*)d_in[0];
    const float* anchors = (const float*)d_in[1];
    const int* ishape = (const int*)d_in[2];
    const float* c1w = (const float*)d_in[3];
    const float* c1b = (const float*)d_in[4];
    const float* clw = (const float*)d_in[5];
    const float* clb = (const float*)d_in[6];
    const float* bxw = (const float*)d_in[7];
    const float* bxb = (const float*)d_in[8];

    char* ws = (char*)d_ws;
    float* y      = (float*)(ws + OFF_Y);
    float* wT     = (float*)(ws + OFF_WT);
    float* zpart  = (float*)(ws + OFF_ZPART);
    float* scores = (float*)(ws + OFF_SCORES);
    float* draw   = (float*)(ws + OFF_DRAW);
    u32*   hist   = (u32*)(ws + OFF_HIST);
    int*   sel    = (int*)(ws + OFF_SEL);
    int*   cnt    = (int*)(ws + OFF_CNT);
    u64*   cand   = (u64*)(ws + OFF_CAND);
    float* topv   = (float*)(ws + OFF_TOPV);
    int*   topi   = (int*)(ws + OFF_TOPI);
    float* boxes  = (float*)(ws + OFF_BOXES);
    u64*   vw     = (u64*)(ws + OFF_VW);
    u64*   mask   = (u64*)(ws + OFF_MASK);
    int*   keepl  = (int*)(ws + OFF_KEEP);
    int*   kc     = (int*)(ws + OFF_KC);
    u64*   kw     = (u64*)(ws + OFF_KW);

    k_wtrans<<<(512 * 512 * 9 + 255) / 256, 256, 0, stream>>>(c1w, wT);
    k_conv1<<<256, 256, 0, stream>>>(x, wT, c1b, y);
    // hist..cand region aliases wT -> memset only after conv consumed wT
    hipMemsetAsync(ws + OFF_HIST, 0, MEMSET_LEN, stream);
    k_heads_part<<<256, 256, 0, stream>>>(y, clw, bxw, zpart);
    k_hreduce<<<(45 * 4096 + 255) / 256, 256, 0, stream>>>(zpart, clb, bxb, scores, draw, hist);
    k_scan_hist<<<1, 1024, 0, stream>>>(hist, sel);
    k_compact<<<(NS + 255) / 256, 256, 0, stream>>>(scores, sel, cand, cnt);
    k_sort<<<1, 1024, 0, stream>>>(cand, topv, topi);
    k_decode<<<24, 256, 0, stream>>>(draw, anchors, ishape, topi, boxes, vw);
    k_mask<<<PRE / 16, 256, 0, stream>>>(boxes, mask);
    k_nms<<<1, 64, 0, stream>>>(mask, vw, keepl, kc, kw);
    k_out<<<1, 384, 0, stream>>>(boxes, topv, keepl, kc, kw, (float*)d_out);
}

// Round 4
// 842.036 us; speedup vs baseline: 1.5065x; 1.5065x over previous
//
#include <hip/hip_runtime.h>
#include <hip/hip_bf16.h>

typedef unsigned int u32;
typedef unsigned long long u64;

// ---------------- workspace layout (bytes) ----------------
// conv phase: y + wT (wT aliases everything below, dead after k_conv1)
#define OFF_Y      0ull             // 8,388,608
#define OFF_WT     8388608ull       // 9,437,184 -> end 17,825,792
// post-conv phase (aliases wT region):
#define OFF_ZPART  8388608ull       // 4*45*4096*4 = 2,949,120
#define OFF_SCORES 11337728ull      // 147,456
#define OFF_DRAW   11485184ull      // 589,824
#define OFF_HIST   12075008ull      // 524,288
#define OFF_SEL    12599296ull      // 256
#define OFF_CNT    12599552ull      // 256
#define OFF_CAND   12599808ull      // 65,536
#define MEMSET_LEN (524288ull + 256ull + 256ull + 65536ull)   // hist..cand
#define OFF_TOPV   12665344ull      // 24,576
#define OFF_TOPI   12689920ull      // 24,576
#define OFF_BOXES  12714496ull      // 98,304
#define OFF_VW     12812800ull      // 1,024
#define OFF_MASK   12813824ull      // 4,608,000 -> 17,421,824
#define OFF_KEEP   17421824ull      // 2,048
#define OFF_KC     17423872ull      // 256
#define OFF_KW     17424128ull      // 1,024

#define NS     36864
#define PRE    6000
#define POST   300
#define SORTN  8192
#define MROW   96   // mask words per row (94 used)

// ================= K0: weight transpose gw[co][ci][k] -> wT[ci][co][k] ======
__global__ __launch_bounds__(256) void k_wtrans(const float* __restrict__ gw,
                                                float* __restrict__ wT) {
    int o = blockIdx.x * 256 + threadIdx.x;   // output index, coalesced write
    if (o >= 512 * 512 * 9) return;
    int ci = o / 4608;
    int r = o - ci * 4608;
    int co = r / 9;
    int k = r - co * 9;
    wT[o] = gw[(co * 512 + ci) * 9 + k];
}

// ================= K1: 3x3 conv 512->512 + bias + relu (v4) =================
// grid 1024 = 32 co-blocks x 32 h-blocks -> 4 blocks/CU (16 waves/CU).
// block 256 = 4 waves; tile 16 co x 2 rows x 64 cols; wave = 4 co.
// weights: VMEM broadcast float4 loads from wT (vmcnt queue, no lgkm drain).
// x: LDS single-buffer 16-ci chunks (16.5 KB); next chunk reg-prefetched.
#define CI 16
#define NROW 4
#define XROW 66
#define CHUNK_ELEMS (CI * NROW * XROW)   // 4224
#define STAGE_IT 17
__global__ __launch_bounds__(256, 4) void k_conv1(const float* __restrict__ x,
                                                  const float* __restrict__ wT,
                                                  const float* __restrict__ gb,
                                                  float* __restrict__ y) {
    __shared__ float xs[CHUNK_ELEMS];   // 16,896 B
    const int t = threadIdx.x;
    const int tx = t & 63;
    const int wv = __builtin_amdgcn_readfirstlane(t >> 6);
    const int cob = (blockIdx.x & 31) << 4;
    const int h0 = (blockIdx.x >> 5) << 1;
    const int co_base = cob + (wv << 2);

    // ---- staging map (constant across chunks; only ci-base shifts)
    int offs[STAGE_IT];
    u32 vmask = 0;
#pragma unroll
    for (int u = 0; u < STAGE_IT; ++u) {
        int idx = t + u * 256;
        offs[u] = 0;
        if (idx < CHUNK_ELEMS) {
            int ci = idx / (NROW * XROW);
            int rem = idx - ci * (NROW * XROW);
            int row = rem / XROW;
            int col = rem - row * XROW;
            int gr = h0 + row - 1, gc = col - 1;
            if ((unsigned)gr < 64u && (unsigned)gc < 64u) {
                offs[u] = ci * 4096 + (gr << 6) + gc;
                vmask |= 1u << u;
            }
        }
    }

    float acc[4][2];
#pragma unroll
    for (int c = 0; c < 4; ++c) { acc[c][0] = 0.f; acc[c][1] = 0.f; }

    float st[STAGE_IT];
#pragma unroll
    for (int u = 0; u < STAGE_IT; ++u)
        st[u] = (vmask >> u & 1) ? x[offs[u]] : 0.f;

    float4 wq[9];
    float xa[12], xb[12];

#pragma unroll 1
    for (int cc = 0; cc < 32; ++cc) {
        if (cc) __syncthreads();   // previous chunk's reads done
#pragma unroll
        for (int u = 0; u < STAGE_IT; ++u) {
            int idx = t + u * 256;
            if (idx < CHUNK_ELEMS) xs[idx] = st[u];
        }
        __syncthreads();
        // prefetch next chunk into regs (latency hidden behind FMA phase)
        if (cc + 1 < 32) {
            const float* xsrc = x + (cc + 1) * CI * 4096;
#pragma unroll
            for (int u = 0; u < STAGE_IT; ++u)
                st[u] = (vmask >> u & 1) ? xsrc[offs[u]] : 0.f;
        }

        const int cig0 = cc * CI;
        // taps for ci=0
        {
            const float* xp = xs + tx;
#pragma unroll
            for (int r = 0; r < NROW; ++r) {
                xa[r * 3 + 0] = xp[r * XROW + 0];
                xa[r * 3 + 1] = xp[r * XROW + 1];
                xa[r * 3 + 2] = xp[r * XROW + 2];
            }
        }
#pragma unroll 1
        for (int ci = 0; ci < CI; ci += 2) {
            // weights ci
            {
                const float4* wp = (const float4*)(wT + ((size_t)(cig0 + ci) * 512 + co_base) * 9);
#pragma unroll
                for (int i = 0; i < 9; ++i) wq[i] = wp[i];
            }
            // taps ci+1 -> xb
            {
                const float* xp = xs + (ci + 1) * (NROW * XROW) + tx;
#pragma unroll
                for (int r = 0; r < NROW; ++r) {
                    xb[r * 3 + 0] = xp[r * XROW + 0];
                    xb[r * 3 + 1] = xp[r * XROW + 1];
                    xb[r * 3 + 2] = xp[r * XROW + 2];
                }
            }
            // FMA ci (xa)
            {
                const float* w = (const float*)wq;
#pragma unroll
                for (int co = 0; co < 4; ++co)
#pragma unroll
                    for (int k = 0; k < 9; ++k) {
                        const int kh = k / 3, kw = k - kh * 3;
                        float wv_ = w[co * 9 + k];
                        acc[co][0] += wv_ * xa[(0 + kh) * 3 + kw];
                        acc[co][1] += wv_ * xa[(1 + kh) * 3 + kw];
                    }
            }
            // weights ci+1
            {
                const float4* wp = (const float4*)(wT + ((size_t)(cig0 + ci + 1) * 512 + co_base) * 9);
#pragma unroll
                for (int i = 0; i < 9; ++i) wq[i] = wp[i];
            }
            // taps ci+2 -> xa (within chunk only)
            if (ci + 2 < CI) {
                const float* xp = xs + (ci + 2) * (NROW * XROW) + tx;
#pragma unroll
                for (int r = 0; r < NROW; ++r) {
                    xa[r * 3 + 0] = xp[r * XROW + 0];
                    xa[r * 3 + 1] = xp[r * XROW + 1];
                    xa[r * 3 + 2] = xp[r * XROW + 2];
                }
            }
            // FMA ci+1 (xb)
            {
                const float* w = (const float*)wq;
#pragma unroll
                for (int co = 0; co < 4; ++co)
#pragma unroll
                    for (int k = 0; k < 9; ++k) {
                        const int kh = k / 3, kw = k - kh * 3;
                        float wv_ = w[co * 9 + k];
                        acc[co][0] += wv_ * xb[(0 + kh) * 3 + kw];
                        acc[co][1] += wv_ * xb[(1 + kh) * 3 + kw];
                    }
            }
        }
    }

#pragma unroll
    for (int co = 0; co < 4; ++co) {
        float bias = gb[co_base + co];
#pragma unroll
        for (int r = 0; r < 2; ++r) {
            float v = acc[co][r] + bias;
            v = v > 0.f ? v : 0.f;
            y[(co_base + co) * 4096 + ((h0 + r) << 6) + tx] = v;
        }
    }
}

// ================= K2a: 1x1 heads, partial over ci quarters =================
// grid 256 = 64 px-chunks x 4 ci-quarters; block 256 = 64 px x 4 wave-groups
__global__ __launch_bounds__(256) void k_heads_part(const float* __restrict__ y,
                                                    const float* __restrict__ cw,
                                                    const float* __restrict__ bw,
                                                    float* __restrict__ zpart) {
    __shared__ float ys[128 * 64];  // 32 KB
    const int t = threadIdx.x;
    const int px = t & 63;
    const int gu = __builtin_amdgcn_readfirstlane(t >> 6);
    const int px0 = (blockIdx.x & 63) << 6;
    const int q = blockIdx.x >> 6;
    const int cib = q << 7;
    const int nch = (gu == 0) ? 12 : 11;

    const float* wrow[12];
#pragma unroll
    for (int j = 0; j < 12; ++j) {
        int ch = gu + 4 * j;
        if (ch < 9) wrow[j] = cw + ch * 512;
        else if (ch < 45) wrow[j] = bw + (ch - 9) * 512;
        else wrow[j] = cw;
    }
    float acc[12];
#pragma unroll
    for (int j = 0; j < 12; ++j) acc[j] = 0.f;

    for (int idx = t; idx < 128 * 64; idx += 256) {
        int ci = idx >> 6;
        int pp = idx & 63;
        ys[idx] = y[(cib + ci) * 4096 + px0 + pp];
    }
    __syncthreads();
    for (int ci = 0; ci < 128; ++ci) {
        float v = ys[ci * 64 + px];
        int cig = cib + ci;
#pragma unroll
        for (int j = 0; j < 12; ++j)
            if (j < nch) acc[j] += v * wrow[j][cig];
    }
    for (int j = 0; j < nch; ++j) {
        int ch = gu + 4 * j;
        zpart[((q * 45 + ch) << 12) + px0 + px] = acc[j];
    }
}

// ================= K2b: reduce partials + bias + sigmoid + hist =============
__global__ __launch_bounds__(256) void k_hreduce(const float* __restrict__ zpart,
                                                 const float* __restrict__ cb,
                                                 const float* __restrict__ bb,
                                                 float* __restrict__ scores,
                                                 float* __restrict__ draw,
                                                 u32* __restrict__ hist) {
    int i = blockIdx.x * 256 + threadIdx.x;
    if (i >= 45 * 4096) return;
    int ch = i >> 12;
    int sp = i & 4095;
    float z = zpart[((0 * 45 + ch) << 12) + sp] + zpart[((1 * 45 + ch) << 12) + sp] +
              zpart[((2 * 45 + ch) << 12) + sp] + zpart[((3 * 45 + ch) << 12) + sp];
    if (ch < 9) {
        z += cb[ch];
        float s = 1.f / (1.f + expf(-z));
        scores[(ch << 12) + sp] = s;
        u32 sb = __float_as_uint(s);
        atomicAdd(&hist[sb >> 13], 1u);
    } else {
        z += bb[ch - 9];
        draw[((ch - 9) << 12) + sp] = z;
    }
}

// ================= K3: find boundary bin (rank 6000 from top), parallel =====
__global__ __launch_bounds__(1024) void k_scan_hist(const u32* __restrict__ hist,
                                                    int* __restrict__ sel) {
    __shared__ u32 csum[1024];
    __shared__ u32 suf[1024];
    int t = threadIdx.x;
    u32 s = 0;
    const u32* hp = hist + t * 128;
    for (int i = 0; i < 128; ++i) s += hp[i];
    csum[t] = s;
    suf[t] = s;
    __syncthreads();
    for (int off = 1; off < 1024; off <<= 1) {
        u32 v = suf[t] + ((t + off < 1024) ? suf[t + off] : 0u);
        __syncthreads();
        suf[t] = v;
        __syncthreads();
    }
    u32 above = suf[t] - csum[t];               // sum of chunks strictly above t
    if (above < (u32)PRE && suf[t] >= (u32)PRE) {
        u32 run = above;
        int bstar = t * 128;
        u32 found = 0;
#pragma unroll 8
        for (int bb2 = 127; bb2 >= 0; --bb2) {
            u32 c = hp[bb2];
            if (!found && run + c >= (u32)PRE) { bstar = t * 128 + bb2; found = 1; }
            if (!found) run += c;
        }
        sel[0] = bstar;
    }
}

// ================= K4: compact candidates (bin >= bstar) =================
__global__ __launch_bounds__(256) void k_compact(const float* __restrict__ scores,
                                                 const int* __restrict__ sel,
                                                 u64* __restrict__ cand,
                                                 int* __restrict__ cnt) {
    int i = blockIdx.x * 256 + threadIdx.x;
    if (i >= NS) return;
    u32 sb = __float_as_uint(scores[i]);
    if ((int)(sb >> 13) >= sel[0]) {
        int pos = atomicAdd(cnt, 1);
        if (pos < SORTN) cand[pos] = ((u64)sb << 32) | (u32)(~i);
    }
}

// ================= K5: bitonic sort 8192 keys (descending) =================
// j<=4 stages done in registers (each thread owns 8 contiguous elements)
__global__ __launch_bounds__(1024) void k_sort(const u64* __restrict__ cand,
                                               float* __restrict__ topv,
                                               int* __restrict__ topi) {
    __shared__ u64 sk[SORTN];  // 64 KB
    const int t = threadIdx.x;
    for (int i = t; i < SORTN; i += 1024) sk[i] = cand[i];
    __syncthreads();

    const int base = t << 3;
    u64 a[8];
    // ---- phases k=2,4,8 entirely in registers
    {
#pragma unroll
        for (int u = 0; u < 8; ++u) a[u] = sk[base + u];
#pragma unroll
        for (int k = 2; k <= 8; k <<= 1) {
#pragma unroll
            for (int j = k >> 1; j > 0; j >>= 1) {
#pragma unroll
                for (int u = 0; u < 8; ++u) {
                    if ((u & j) == 0) {
                        int l = u | j;
                        bool up = (((base + u) & k) == 0);
                        u64 x0 = a[u], x1 = a[l];
                        if (up ? (x0 < x1) : (x0 > x1)) { a[u] = x1; a[l] = x0; }
                    }
                }
            }
        }
#pragma unroll
        for (int u = 0; u < 8; ++u) sk[base + u] = a[u];
        __syncthreads();
    }
    // ---- phases k=16..8192
    for (int k = 16; k <= SORTN; k <<= 1) {
        for (int j = k >> 1; j >= 8; j >>= 1) {
#pragma unroll
            for (int s = 0; s < 4; ++s) {
                int pidx = t + (s << 10);
                int i = ((pidx & ~(j - 1)) << 1) | (pidx & (j - 1));
                int l = i | j;
                u64 x0 = sk[i], x1 = sk[l];
                bool up = ((i & k) == 0);
                if (up ? (x0 < x1) : (x0 > x1)) { sk[i] = x1; sk[l] = x0; }
            }
            __syncthreads();
        }
        // j = 4,2,1 in registers
#pragma unroll
        for (int u = 0; u < 8; ++u) a[u] = sk[base + u];
        {
            bool up = ((base & k) == 0);   // uniform across the 8 (k>=16)
#pragma unroll
            for (int j = 4; j > 0; j >>= 1) {
#pragma unroll
                for (int u = 0; u < 8; ++u) {
                    if ((u & j) == 0) {
                        int l = u | j;
                        u64 x0 = a[u], x1 = a[l];
                        if (up ? (x0 < x1) : (x0 > x1)) { a[u] = x1; a[l] = x0; }
                    }
                }
            }
        }
#pragma unroll
        for (int u = 0; u < 8; ++u) sk[base + u] = a[u];
        __syncthreads();
    }

    for (int r = t; r < PRE; r += 1024) {
        u64 key = sk[r];
        topv[r] = __uint_as_float((u32)(key >> 32));
        topi[r] = (int)(~(u32)key);
    }
}

// ================= K6: decode + clip + valid bitmask =================
__global__ __launch_bounds__(256) void k_decode(const float* __restrict__ draw,
                                                const float* __restrict__ anchors,
                                                const int* __restrict__ ishape,
                                                const int* __restrict__ topi,
                                                float* __restrict__ boxes,
                                                u64* __restrict__ vw) {
    int r = blockIdx.x * 256 + threadIdx.x;
    bool valid = false;
    if (r < PRE) {
        int i = topi[r];
        int c = i >> 10;
        int t4 = i & 1023;
        int base = c * 4096 + (t4 << 2);
        float dx = draw[base], dy = draw[base + 1];
        float dw = draw[base + 2], dh = draw[base + 3];
        const float* a = anchors + i * 4;
        float aw = a[2] - a[0], ah = a[3] - a[1];
        float ax = a[0] + 0.5f * aw, ay = a[1] + 0.5f * ah;
        const float CLIPV = (float)4.135166556742356;
        dw = fminf(dw, CLIPV);
        dh = fminf(dh, CLIPV);
        float px = dx * aw + ax, py = dy * ah + ay;
        float pw = expf(dw) * aw, ph = expf(dh) * ah;
        float wimg = (float)ishape[1], himg = (float)ishape[0];
        float x1 = fminf(fmaxf(px - 0.5f * pw, 0.f), wimg);
        float y1 = fminf(fmaxf(py - 0.5f * ph, 0.f), himg);
        float x2 = fminf(fmaxf(px + 0.5f * pw, 0.f), wimg);
        float y2 = fminf(fmaxf(py + 0.5f * ph, 0.f), himg);
        valid = (x2 - x1 >= 16.f) && (y2 - y1 >= 16.f);
        *(float4*)(boxes + r * 4) = make_float4(x1, y1, x2, y2);
    }
    u64 bm = __ballot(valid);
    if ((threadIdx.x & 63) == 0) vw[r >> 6] = bm;
}

// ================= K7: suppression bitmask (iou > 0.7, j > row) =============
__global__ __launch_bounds__(256) void k_mask(const float* __restrict__ boxes,
                                              u64* __restrict__ mask) {
    __shared__ float4 cbx[16 * 65];
    const int t = threadIdx.x;
    const int r0 = blockIdx.x << 4;
    const int row = r0 + (t >> 4);
    const int wloc = t & 15;
    float4 rb = *(const float4*)(boxes + row * 4);
    float area_a = (rb.z - rb.x) * (rb.w - rb.y);
    for (int chunk = 0; chunk < 6; ++chunk) {
        int j0c = chunk << 10;
        for (int idx = t; idx < 1024; idx += 256) {
            int j = j0c + idx;
            float4 v = make_float4(0.f, 0.f, 0.f, 0.f);
            if (j < PRE) v = *(const float4*)(boxes + j * 4);
            cbx[(idx >> 6) * 65 + (idx & 63)] = v;
        }
        __syncthreads();
        u64 bits = 0;
        const float4* cbr = cbx + wloc * 65;
        for (int b = 0; b < 64; ++b) {
            int j = j0c + (wloc << 6) + b;
            float4 ob = cbr[b];
            float area_b = (ob.z - ob.x) * (ob.w - ob.y);
            float ltx = fmaxf(rb.x, ob.x), lty = fmaxf(rb.y, ob.y);
            float rbx = fminf(rb.z, ob.z), rby = fminf(rb.w, ob.w);
            float wx = fmaxf(rbx - ltx, 0.f), wy = fmaxf(rby - lty, 0.f);
            float inter = wx * wy;
            float uni = area_a + area_b - inter;
            float iou = (uni > 0.f) ? (inter / uni) : 0.f;
            if (iou > 0.7f && j > row && j < PRE) bits |= (1ull << b);
        }
        mask[(size_t)row * MROW + (chunk << 4) + wloc] = bits;
        __syncthreads();
    }
}

// ================= K8: serial greedy NMS, batch-16 LDS row prefetch =========
__global__ __launch_bounds__(64) void k_nms(const u64* __restrict__ mask,
                                            const u64* __restrict__ vw,
                                            int* __restrict__ keeplist,
                                            int* __restrict__ kc_out,
                                            u64* __restrict__ kw_out) {
    __shared__ u64 rem[MROW];
    __shared__ u64 rows16[16][MROW];   // 12,288 B
    const int lane = threadIdx.x;
    for (int qd = lane; qd < MROW; qd += 64) rem[qd] = 0ull;
    __syncthreads();
    int kc = 0;
    bool done = false;
    for (int w = 0; w < 94 && !done; ++w) {
        u64 aw = vw[w] & ~rem[w];
        u64 kwbits = 0;
        while (aw != 0ull && !done) {
            // extract up to 16 lowest set bits (uniform across lanes)
            int bq[16];
            u64 tmp = aw;
#pragma unroll
            for (int q2 = 0; q2 < 16; ++q2) {
                bq[q2] = tmp ? __builtin_ctzll(tmp) : 64;
                tmp &= tmp - 1;
            }
            // cooperative prefetch of those rows into LDS
#pragma unroll
            for (int u = 0; u < 24; ++u) {
                int i = lane + u * 64;
                int q2 = i / MROW;
                int ww = i - q2 * MROW;
                if (bq[q2] < 64)
                    rows16[q2][ww] = mask[(size_t)((w << 6) + bq[q2]) * MROW + ww];
            }
            __syncthreads();
            // serial resolve
            for (int q2 = 0; q2 < 16; ++q2) {
                int b = bq[q2];
                if (b >= 64) break;
                if (!((aw >> b) & 1ull)) continue;   // suppressed within batch
                if (lane == 0) keeplist[kc] = (w << 6) + b;
                kc++;
                kwbits |= (1ull << b);
                if (kc >= POST) { done = true; break; }
                rem[lane] |= rows16[q2][lane];
                if (lane < MROW - 64) rem[64 + lane] |= rows16[q2][64 + lane];
                aw &= ~rows16[q2][w];
                aw &= ~(1ull << b);
            }
            __syncthreads();
        }
        if (lane == 0) kw_out[w] = kwbits;
        __syncthreads();
    }
    if (lane == 0) *kc_out = kc;
}

// ================= K9: write 300 boxes + scores =================
__global__ __launch_bounds__(384) void k_out(const float* __restrict__ boxes,
                                             const float* __restrict__ topv,
                                             const int* __restrict__ keeplist,
                                             const int* __restrict__ kc_p,
                                             const u64* __restrict__ kw,
                                             float* __restrict__ out) {
    int j = threadIdx.x;
    if (j >= POST) return;
    int kc = *kc_p;
    int r;
    float sc;
    if (j < kc) {
        r = keeplist[j];
        sc = topv[r];
    } else {
        int target = j - kc;
        r = PRE - 1;
        int cum = 0;
        for (int w = 0; w < 94; ++w) {
            u64 kb = kw[w];
            int nvalid = (w < 93) ? 64 : 48;
            u64 vmask2 = (nvalid == 64) ? ~0ull : ((1ull << nvalid) - 1ull);
            u64 nk = (~kb) & vmask2;
            int c = __popcll(nk);
            if (cum + c > target) {
                int need = target - cum;
                u64 m = nk;
                for (int q = 0; q < need; ++q) m &= (m - 1);
                r = (w << 6) + __builtin_ctzll(m);
                break;
            }
            cum += c;
        }
        sc = -1.0f;
    }
    out[j * 4 + 0] = boxes[r * 4 + 0];
    out[j * 4 + 1] = boxes[r * 4 + 1];
    out[j * 4 + 2] = boxes[r * 4 + 2];
    out[j * 4 + 3] = boxes[r * 4 + 3];
    out[1200 + j] = sc;
}

extern "C" void kernel_launch(void* const* d_in, const int* in_sizes, int n_in,
                              void* d_out, int out_size, void* d_ws, size_t ws_size,
                              hipStream_t stream) {
    const float* x = (const float*)d_in[0];
    const float* anchors = (const float*)d_in[1];
    const int* ishape = (const int*)d_in[2];
    const float* c1w = (const float*)d_in[3];
    const float* c1b = (const float*)d_in[4];
    const float* clw = (const float*)d_in[5];
    const float* clb = (const float*)d_in[6];
    const float* bxw = (const float*)d_in[7];
    const float* bxb = (const float*)d_in[8];

    char* ws = (char*)d_ws;
    float* y      = (float*)(ws + OFF_Y);
    float* wT     = (float*)(ws + OFF_WT);
    float* zpart  = (float*)(ws + OFF_ZPART);
    float* scores = (float*)(ws + OFF_SCORES);
    float* draw   = (float*)(ws + OFF_DRAW);
    u32*   hist   = (u32*)(ws + OFF_HIST);
    int*   sel    = (int*)(ws + OFF_SEL);
    int*   cnt    = (int*)(ws + OFF_CNT);
    u64*   cand   = (u64*)(ws + OFF_CAND);
    float* topv   = (float*)(ws + OFF_TOPV);
    int*   topi   = (int*)(ws + OFF_TOPI);
    float* boxes  = (float*)(ws + OFF_BOXES);
    u64*   vw     = (u64*)(ws + OFF_VW);
    u64*   mask   = (u64*)(ws + OFF_MASK);
    int*   keepl  = (int*)(ws + OFF_KEEP);
    int*   kc     = (int*)(ws + OFF_KC);
    u64*   kw     = (u64*)(ws + OFF_KW);

    k_wtrans<<<(512 * 512 * 9 + 255) / 256, 256, 0, stream>>>(c1w, wT);
    k_conv1<<<1024, 256, 0, stream>>>(x, wT, c1b, y);
    // hist..cand region aliases wT -> memset only after conv consumed wT
    hipMemsetAsync(ws + OFF_HIST, 0, MEMSET_LEN, stream);
    k_heads_part<<<256, 256, 0, stream>>>(y, clw, bxw, zpart);
    k_hreduce<<<(45 * 4096 + 255) / 256, 256, 0, stream>>>(zpart, clb, bxb, scores, draw, hist);
    k_scan_hist<<<1, 1024, 0, stream>>>(hist, sel);
    k_compact<<<(NS + 255) / 256, 256, 0, stream>>>(scores, sel, cand, cnt);
    k_sort<<<1, 1024, 0, stream>>>(cand, topv, topi);
    k_decode<<<24, 256, 0, stream>>>(draw, anchors, ishape, topi, boxes, vw);
    k_mask<<<PRE / 16, 256, 0, stream>>>(boxes, mask);
    k_nms<<<1, 64, 0, stream>>>(mask, vw, keepl, kc, kw);
    k_out<<<1, 384, 0, stream>>>(boxes, topv, keepl, kc, kw, (float*)d_out);
}

// Round 5
// 773.699 us; speedup vs baseline: 1.6395x; 1.0883x over previous
//
#include <hip/hip_runtime.h>
#include <hip/hip_bf16.h>

typedef unsigned int u32;
typedef unsigned long long u64;

// ---------------- workspace layout (bytes) ----------------
// conv phase: y + wT (wT aliases everything below, dead after k_conv1)
#define OFF_Y      0ull             // 8,388,608
#define OFF_WT     8388608ull       // 9,437,184 -> end 17,825,792
// post-conv phase (aliases wT region):
#define OFF_ZPART  8388608ull       // 4*45*4096*4 = 2,949,120
#define OFF_SCORES 11337728ull      // 147,456
#define OFF_DRAW   11485184ull      // 589,824
#define OFF_HIST   12075008ull      // 524,288
#define MEMSET_LEN 524288ull        // hist only
#define OFF_TOPV   12665344ull      // 24,576
#define OFF_BOXES  12714496ull      // 98,304
#define OFF_VW     12812800ull      // 1,024
#define OFF_MASK   12813824ull      // 6000*96*8 = 4,608,000 -> 17,421,824

#define NS     36864
#define PRE    6000
#define POST   300
#define SORTN  8192
#define MROW   96   // mask words per row (94 used)

// ================= K0: weight transpose gw[co][ci][k] -> wT[ci][co][k] ======
__global__ __launch_bounds__(256) void k_wtrans(const float* __restrict__ gw,
                                                float* __restrict__ wT) {
    int o = blockIdx.x * 256 + threadIdx.x;   // output index, coalesced write
    if (o >= 512 * 512 * 9) return;
    int ci = o / 4608;
    int r = o - ci * 4608;
    int co = r / 9;
    int k = r - co * 9;
    wT[o] = gw[(co * 512 + ci) * 9 + k];
}

// ================= K1: 3x3 conv 512->512 + bias + relu (v5) =================
// grid 512 = 16 co-blocks x 32 h-blocks -> 2 blocks/CU (8 waves/CU).
// block 256 = 4 waves; tile 32 co x 2 rows x 64 cols; wave = 8 co x 2 rows.
// co=8/wave doubles FMA per tap-read vs v4: DS pipe 1.3x-over -> 0.65x.
// weights: VMEM broadcast float4 (quad-serial: 9 float4 per co-quad).
#define CI 16
#define NROW 4
#define XROW 66
#define CHUNK_ELEMS (CI * NROW * XROW)   // 4224
#define STAGE_IT 17
__global__ __launch_bounds__(256) void k_conv1(const float* __restrict__ x,
                                               const float* __restrict__ wT,
                                               const float* __restrict__ gb,
                                               float* __restrict__ y) {
    __shared__ float xs[CHUNK_ELEMS];   // 16,896 B
    const int t = threadIdx.x;
    const int tx = t & 63;
    const int wv = __builtin_amdgcn_readfirstlane(t >> 6);
    const int cob = (blockIdx.x & 15) << 5;
    const int h0 = (blockIdx.x >> 4) << 1;
    const int co_base = cob + (wv << 3);   // 8 co per wave

    // staging map (constant across chunks; only ci-base shifts)
    int offs[STAGE_IT];
    u32 vmask = 0;
#pragma unroll
    for (int u = 0; u < STAGE_IT; ++u) {
        int idx = t + u * 256;
        offs[u] = 0;
        if (idx < CHUNK_ELEMS) {
            int ci = idx / (NROW * XROW);
            int rem = idx - ci * (NROW * XROW);
            int row = rem / XROW;
            int col = rem - row * XROW;
            int gr = h0 + row - 1, gc = col - 1;
            if ((unsigned)gr < 64u && (unsigned)gc < 64u) {
                offs[u] = ci * 4096 + (gr << 6) + gc;
                vmask |= 1u << u;
            }
        }
    }

    float acc[8][2];
#pragma unroll
    for (int c = 0; c < 8; ++c) { acc[c][0] = 0.f; acc[c][1] = 0.f; }

    float st[STAGE_IT];
#pragma unroll
    for (int u = 0; u < STAGE_IT; ++u)
        st[u] = (vmask >> u & 1) ? x[offs[u]] : 0.f;

#pragma unroll 1
    for (int cc = 0; cc < 32; ++cc) {
        if (cc) __syncthreads();
#pragma unroll
        for (int u = 0; u < STAGE_IT; ++u) {
            int idx = t + u * 256;
            if (idx < CHUNK_ELEMS) xs[idx] = st[u];
        }
        __syncthreads();
        if (cc + 1 < 32) {
            const float* xsrc = x + (cc + 1) * CI * 4096;
#pragma unroll
            for (int u = 0; u < STAGE_IT; ++u)
                st[u] = (vmask >> u & 1) ? xsrc[offs[u]] : 0.f;
        }

        const int cig0 = cc * CI;
#pragma unroll 1
        for (int ci = 0; ci < CI; ++ci) {
            float xr[12];
            {
                const float* xp = xs + ci * (NROW * XROW) + tx;
#pragma unroll
                for (int r = 0; r < NROW; ++r) {
                    xr[r * 3 + 0] = xp[r * XROW + 0];
                    xr[r * 3 + 1] = xp[r * XROW + 1];
                    xr[r * 3 + 2] = xp[r * XROW + 2];
                }
            }
            const float* wbase = wT + ((size_t)(cig0 + ci) * 512 + co_base) * 9;
            // co-quad 0
            {
                float4 wq[9];
                const float4* wp = (const float4*)wbase;
#pragma unroll
                for (int i = 0; i < 9; ++i) wq[i] = wp[i];
                const float* w = (const float*)wq;
#pragma unroll
                for (int co = 0; co < 4; ++co)
#pragma unroll
                    for (int k = 0; k < 9; ++k) {
                        const int kh = k / 3, kw = k - kh * 3;
                        float wv_ = w[co * 9 + k];
                        acc[co][0] += wv_ * xr[(0 + kh) * 3 + kw];
                        acc[co][1] += wv_ * xr[(1 + kh) * 3 + kw];
                    }
            }
            // co-quad 1
            {
                float4 wq[9];
                const float4* wp = (const float4*)(wbase + 36);
#pragma unroll
                for (int i = 0; i < 9; ++i) wq[i] = wp[i];
                const float* w = (const float*)wq;
#pragma unroll
                for (int co = 0; co < 4; ++co)
#pragma unroll
                    for (int k = 0; k < 9; ++k) {
                        const int kh = k / 3, kw = k - kh * 3;
                        float wv_ = w[co * 9 + k];
                        acc[co + 4][0] += wv_ * xr[(0 + kh) * 3 + kw];
                        acc[co + 4][1] += wv_ * xr[(1 + kh) * 3 + kw];
                    }
            }
        }
    }

#pragma unroll
    for (int co = 0; co < 8; ++co) {
        float bias = gb[co_base + co];
#pragma unroll
        for (int r = 0; r < 2; ++r) {
            float v = acc[co][r] + bias;
            v = v > 0.f ? v : 0.f;
            y[(co_base + co) * 4096 + ((h0 + r) << 6) + tx] = v;
        }
    }
}

// ================= K2a: 1x1 heads, partial over ci quarters =================
// grid 256 = 64 px-chunks x 4 ci-quarters; block 256 = 64 px x 4 wave-groups.
// y staged TRANSPOSED [px][ci] (pad 132) -> ds_read_b128 per ci-quad; weights
// via float4 VMEM (vmcnt queue, no SMEM out-of-order lgkm serialization).
__global__ __launch_bounds__(256) void k_heads_part(const float* __restrict__ y,
                                                    const float* __restrict__ cw,
                                                    const float* __restrict__ bw,
                                                    float* __restrict__ zpart) {
    __shared__ __align__(16) float ys[64][132];  // 33,792 B
    const int t = threadIdx.x;
    const int px = t & 63;
    const int gu = __builtin_amdgcn_readfirstlane(t >> 6);
    const int px0 = (blockIdx.x & 63) << 6;
    const int q = blockIdx.x >> 6;
    const int cib = q << 7;
    const int nch = (gu == 0) ? 12 : 11;

    const float* wrow[12];
#pragma unroll
    for (int j = 0; j < 12; ++j) {
        int ch = gu + 4 * j;
        if (ch < 9) wrow[j] = cw + ch * 512;
        else if (ch < 45) wrow[j] = bw + (ch - 9) * 512;
        else wrow[j] = cw;
    }
    float acc[12];
#pragma unroll
    for (int j = 0; j < 12; ++j) acc[j] = 0.f;

    for (int idx = t; idx < 128 * 64; idx += 256) {
        int ci = idx >> 6;
        int pp = idx & 63;
        ys[pp][ci] = y[(cib + ci) * 4096 + px0 + pp];
    }
    __syncthreads();

#pragma unroll 1
    for (int cq = 0; cq < 32; ++cq) {
        float4 yv = *(const float4*)&ys[px][cq << 2];
        float4 wv[12];
#pragma unroll
        for (int j = 0; j < 12; ++j)
            if (j < nch) wv[j] = *(const float4*)(wrow[j] + cib + (cq << 2));
#pragma unroll
        for (int j = 0; j < 12; ++j)
            if (j < nch)
                acc[j] += wv[j].x * yv.x + wv[j].y * yv.y + wv[j].z * yv.z + wv[j].w * yv.w;
    }
    for (int j = 0; j < nch; ++j) {
        int ch = gu + 4 * j;
        zpart[((q * 45 + ch) << 12) + px0 + px] = acc[j];
    }
}

// ================= K2b: reduce partials + bias + sigmoid + hist =============
__global__ __launch_bounds__(256) void k_hreduce(const float* __restrict__ zpart,
                                                 const float* __restrict__ cb,
                                                 const float* __restrict__ bb,
                                                 float* __restrict__ scores,
                                                 float* __restrict__ draw,
                                                 u32* __restrict__ hist) {
    int i = blockIdx.x * 256 + threadIdx.x;
    if (i >= 45 * 4096) return;
    int ch = i >> 12;
    int sp = i & 4095;
    float z = zpart[((0 * 45 + ch) << 12) + sp] + zpart[((1 * 45 + ch) << 12) + sp] +
              zpart[((2 * 45 + ch) << 12) + sp] + zpart[((3 * 45 + ch) << 12) + sp];
    if (ch < 9) {
        z += cb[ch];
        float s = 1.f / (1.f + expf(-z));
        scores[(ch << 12) + sp] = s;
        u32 sb = __float_as_uint(s);
        atomicAdd(&hist[sb >> 13], 1u);
    } else {
        z += bb[ch - 9];
        draw[((ch - 9) << 12) + sp] = z;
    }
}

// ======== K3: fused select = hist-scan + compact + bitonic sort + decode ====
// 1 block, 1024 threads. sort array lives in LDS (64 KB); no global cand.
__global__ __launch_bounds__(1024) void k_select(const u32* __restrict__ hist,
                                                 const float* __restrict__ scores,
                                                 const float* __restrict__ draw,
                                                 const float* __restrict__ anchors,
                                                 const int* __restrict__ ishape,
                                                 float* __restrict__ boxes,
                                                 float* __restrict__ topv,
                                                 u64* __restrict__ vw) {
    __shared__ u32 csum[1024];
    __shared__ u32 suf[1024];
    __shared__ u64 sk[SORTN];   // 64 KB
    __shared__ int sel_s, cnt_s;
    const int t = threadIdx.x;

    // ---- suffix-scan of 131072-bin histogram -> boundary bin (rank 6000)
    u32 s = 0;
    const u32* hp = hist + t * 128;
    for (int i = 0; i < 128; ++i) s += hp[i];
    csum[t] = s;
    suf[t] = s;
    if (t == 0) cnt_s = 0;
    __syncthreads();
    for (int off = 1; off < 1024; off <<= 1) {
        u32 v = suf[t] + ((t + off < 1024) ? suf[t + off] : 0u);
        __syncthreads();
        suf[t] = v;
        __syncthreads();
    }
    u32 above = suf[t] - csum[t];
    if (above < (u32)PRE && suf[t] >= (u32)PRE) {
        u32 run = above;
        int bstar = t * 128;
        u32 found = 0;
        for (int b2 = 127; b2 >= 0; --b2) {
            u32 c = hp[b2];
            if (!found && run + c >= (u32)PRE) { bstar = t * 128 + b2; found = 1; }
            if (!found) run += c;
        }
        sel_s = bstar;
    }
    for (int i = t; i < SORTN; i += 1024) sk[i] = 0;
    __syncthreads();

    // ---- compact candidates into LDS
    const int sel = sel_s;
    for (int i = t; i < NS; i += 1024) {
        u32 sb = __float_as_uint(scores[i]);
        if ((int)(sb >> 13) >= sel) {
            int p = atomicAdd(&cnt_s, 1);
            if (p < SORTN) sk[p] = ((u64)sb << 32) | (u32)(~i);
        }
    }
    __syncthreads();

    // ---- bitonic sort 8192 (descending), j<=4 stages in registers
    const int base = t << 3;
    u64 a[8];
    {
#pragma unroll
        for (int u = 0; u < 8; ++u) a[u] = sk[base + u];
#pragma unroll
        for (int k = 2; k <= 8; k <<= 1) {
#pragma unroll
            for (int j = k >> 1; j > 0; j >>= 1) {
#pragma unroll
                for (int u = 0; u < 8; ++u) {
                    if ((u & j) == 0) {
                        int l = u | j;
                        bool up = (((base + u) & k) == 0);
                        u64 x0 = a[u], x1 = a[l];
                        if (up ? (x0 < x1) : (x0 > x1)) { a[u] = x1; a[l] = x0; }
                    }
                }
            }
        }
#pragma unroll
        for (int u = 0; u < 8; ++u) sk[base + u] = a[u];
        __syncthreads();
    }
    for (int k = 16; k <= SORTN; k <<= 1) {
        for (int j = k >> 1; j >= 8; j >>= 1) {
#pragma unroll
            for (int s2 = 0; s2 < 4; ++s2) {
                int pidx = t + (s2 << 10);
                int i = ((pidx & ~(j - 1)) << 1) | (pidx & (j - 1));
                int l = i | j;
                u64 x0 = sk[i], x1 = sk[l];
                bool up = ((i & k) == 0);
                if (up ? (x0 < x1) : (x0 > x1)) { sk[i] = x1; sk[l] = x0; }
            }
            __syncthreads();
        }
#pragma unroll
        for (int u = 0; u < 8; ++u) a[u] = sk[base + u];
        {
            bool up = ((base & k) == 0);
#pragma unroll
            for (int j = 4; j > 0; j >>= 1) {
#pragma unroll
                for (int u = 0; u < 8; ++u) {
                    if ((u & j) == 0) {
                        int l = u | j;
                        u64 x0 = a[u], x1 = a[l];
                        if (up ? (x0 < x1) : (x0 > x1)) { a[u] = x1; a[l] = x0; }
                    }
                }
            }
        }
#pragma unroll
        for (int u = 0; u < 8; ++u) sk[base + u] = a[u];
        __syncthreads();
    }

    // ---- decode + clip + valid ballot -> boxes, topv, vw
    const float wimg = (float)ishape[1], himg = (float)ishape[0];
#pragma unroll 1
    for (int s2 = 0; s2 < 6; ++s2) {
        int r = (s2 << 10) + t;
        bool valid = false;
        if (r < PRE) {
            u64 key = sk[r];
            u32 sb = (u32)(key >> 32);
            int i = (int)(~(u32)key);
            topv[r] = __uint_as_float(sb);
            int c = i >> 10;
            int t4 = i & 1023;
            float4 d4 = *(const float4*)(draw + c * 4096 + (t4 << 2));
            float4 a4 = *(const float4*)(anchors + i * 4);
            float aw = a4.z - a4.x, ah = a4.w - a4.y;
            float ax = a4.x + 0.5f * aw, ay = a4.y + 0.5f * ah;
            const float CLIPV = (float)4.135166556742356;
            float dw = fminf(d4.z, CLIPV);
            float dh = fminf(d4.w, CLIPV);
            float px = d4.x * aw + ax, py = d4.y * ah + ay;
            float pw = expf(dw) * aw, ph = expf(dh) * ah;
            float x1 = fminf(fmaxf(px - 0.5f * pw, 0.f), wimg);
            float y1 = fminf(fmaxf(py - 0.5f * ph, 0.f), himg);
            float x2 = fminf(fmaxf(px + 0.5f * pw, 0.f), wimg);
            float y2 = fminf(fmaxf(py + 0.5f * ph, 0.f), himg);
            valid = (x2 - x1 >= 16.f) && (y2 - y1 >= 16.f);
            *(float4*)(boxes + r * 4) = make_float4(x1, y1, x2, y2);
        }
        u64 bm = __ballot(valid);
        if ((t & 63) == 0) vw[(s2 << 4) + (t >> 6)] = bm;
    }
}

// ================= K4: suppression bitmask (iou > 0.7, j > row) =============
__global__ __launch_bounds__(256) void k_mask(const float* __restrict__ boxes,
                                              u64* __restrict__ mask) {
    __shared__ float4 cbx[16 * 65];
    const int t = threadIdx.x;
    const int r0 = blockIdx.x << 4;
    const int row = r0 + (t >> 4);
    const int wloc = t & 15;
    float4 rb = *(const float4*)(boxes + row * 4);
    float area_a = (rb.z - rb.x) * (rb.w - rb.y);
    for (int chunk = 0; chunk < 6; ++chunk) {
        int j0c = chunk << 10;
        for (int idx = t; idx < 1024; idx += 256) {
            int j = j0c + idx;
            float4 v = make_float4(0.f, 0.f, 0.f, 0.f);
            if (j < PRE) v = *(const float4*)(boxes + j * 4);
            cbx[(idx >> 6) * 65 + (idx & 63)] = v;
        }
        __syncthreads();
        u64 bits = 0;
        const float4* cbr = cbx + wloc * 65;
        for (int b = 0; b < 64; ++b) {
            int j = j0c + (wloc << 6) + b;
            float4 ob = cbr[b];
            float area_b = (ob.z - ob.x) * (ob.w - ob.y);
            float ltx = fmaxf(rb.x, ob.x), lty = fmaxf(rb.y, ob.y);
            float rbx = fminf(rb.z, ob.z), rby = fminf(rb.w, ob.w);
            float wx = fmaxf(rbx - ltx, 0.f), wy = fmaxf(rby - lty, 0.f);
            float inter = wx * wy;
            float uni = area_a + area_b - inter;
            float iou = (uni > 0.f) ? (inter / uni) : 0.f;
            if (iou > 0.7f && j > row && j < PRE) bits |= (1ull << b);
        }
        mask[(size_t)row * MROW + (chunk << 4) + wloc] = bits;
        __syncthreads();
    }
}

// ======== K5: fused NMS (serial greedy, batch-16 prefetch) + output write ===
// block 320 (5 waves), uniform control flow; all threads follow the scan,
// lane-specific work guarded by tid. Early-stop at 300 keeps.
__global__ __launch_bounds__(320) void k_nms_out(const u64* __restrict__ mask,
                                                 const u64* __restrict__ vw,
                                                 const float* __restrict__ boxes,
                                                 const float* __restrict__ topv,
                                                 float* __restrict__ out) {
    __shared__ u64 rem[MROW];
    __shared__ u64 rows16[16][MROW];   // 12,288 B
    __shared__ u64 kws[MROW];
    __shared__ int keepl[POST];
    const int tid = threadIdx.x;
    for (int i = tid; i < MROW; i += 320) { rem[i] = 0ull; kws[i] = 0ull; }
    __syncthreads();
    int kc = 0;
    bool done = false;
    for (int w = 0; w < 94 && !done; ++w) {
        u64 aw = vw[w] & ~rem[w];
        u64 kwbits = 0;
        while (aw != 0ull && !done) {
            int bq[16];
            u64 tmp = aw;
#pragma unroll
            for (int q2 = 0; q2 < 16; ++q2) {
                bq[q2] = tmp ? __builtin_ctzll(tmp) : 64;
                tmp &= tmp - 1;
            }
#pragma unroll
            for (int u = 0; u < 5; ++u) {
                int i = tid + u * 320;
                if (i < 16 * MROW) {
                    int q2 = i / MROW;
                    int ww = i - q2 * MROW;
                    if (bq[q2] < 64)
                        rows16[q2][ww] = mask[(size_t)((w << 6) + bq[q2]) * MROW + ww];
                }
            }
            __syncthreads();
            for (int q2 = 0; q2 < 16; ++q2) {
                int b = bq[q2];
                if (b >= 64) break;
                if (!((aw >> b) & 1ull)) continue;
                if (tid == 0) keepl[kc] = (w << 6) + b;
                kc++;
                kwbits |= (1ull << b);
                if (kc >= POST) { done = true; break; }
                if (tid < MROW) rem[tid] |= rows16[q2][tid];
                aw &= ~rows16[q2][w];
                aw &= ~(1ull << b);
            }
            __syncthreads();
        }
        if (tid == 0) kws[w] = kwbits;
        __syncthreads();
    }
    __syncthreads();

    // ---- output phase (300 boxes + scores)
    int j = tid;
    if (j >= POST) return;
    int r;
    float sc;
    if (j < kc) {
        r = keepl[j];
        sc = topv[r];
    } else {
        int target = j - kc;
        r = PRE - 1;
        int cum = 0;
        for (int w = 0; w < 94; ++w) {
            u64 kb = kws[w];
            int nvalid = (w < 93) ? 64 : 48;
            u64 vmask2 = (nvalid == 64) ? ~0ull : ((1ull << nvalid) - 1ull);
            u64 nk = (~kb) & vmask2;
            int c = __popcll(nk);
            if (cum + c > target) {
                int need = target - cum;
                u64 m = nk;
                for (int q = 0; q < need; ++q) m &= (m - 1);
                r = (w << 6) + __builtin_ctzll(m);
                break;
            }
            cum += c;
        }
        sc = -1.0f;
    }
    out[j * 4 + 0] = boxes[r * 4 + 0];
    out[j * 4 + 1] = boxes[r * 4 + 1];
    out[j * 4 + 2] = boxes[r * 4 + 2];
    out[j * 4 + 3] = boxes[r * 4 + 3];
    out[1200 + j] = sc;
}

extern "C" void kernel_launch(void* const* d_in, const int* in_sizes, int n_in,
                              void* d_out, int out_size, void* d_ws, size_t ws_size,
                              hipStream_t stream) {
    const float* x = (const float*)d_in[0];
    const float* anchors = (const float*)d_in[1];
    const int* ishape = (const int*)d_in[2];
    const float* c1w = (const float*)d_in[3];
    const float* c1b = (const float*)d_in[4];
    const float* clw = (const float*)d_in[5];
    const float* clb = (const float*)d_in[6];
    const float* bxw = (const float*)d_in[7];
    const float* bxb = (const float*)d_in[8];

    char* ws = (char*)d_ws;
    float* y      = (float*)(ws + OFF_Y);
    float* wT     = (float*)(ws + OFF_WT);
    float* zpart  = (float*)(ws + OFF_ZPART);
    float* scores = (float*)(ws + OFF_SCORES);
    float* draw   = (float*)(ws + OFF_DRAW);
    u32*   hist   = (u32*)(ws + OFF_HIST);
    float* topv   = (float*)(ws + OFF_TOPV);
    float* boxes  = (float*)(ws + OFF_BOXES);
    u64*   vw     = (u64*)(ws + OFF_VW);
    u64*   mask   = (u64*)(ws + OFF_MASK);

    k_wtrans<<<(512 * 512 * 9 + 255) / 256, 256, 0, stream>>>(c1w, wT);
    k_conv1<<<512, 256, 0, stream>>>(x, wT, c1b, y);
    // hist region aliases wT -> memset only after conv consumed wT
    hipMemsetAsync(ws + OFF_HIST, 0, MEMSET_LEN, stream);
    k_heads_part<<<256, 256, 0, stream>>>(y, clw, bxw, zpart);
    k_hreduce<<<(45 * 4096 + 255) / 256, 256, 0, stream>>>(zpart, clb, bxb, scores, draw, hist);
    k_select<<<1, 1024, 0, stream>>>(hist, scores, draw, anchors, ishape, boxes, topv, vw);
    k_mask<<<PRE / 16, 256, 0, stream>>>(boxes, mask);
    k_nms_out<<<1, 320, 0, stream>>>(mask, vw, boxes, topv, (float*)d_out);
}

// Round 6
// 712.858 us; speedup vs baseline: 1.7795x; 1.0853x over previous
//
#include <hip/hip_runtime.h>
#include <hip/hip_bf16.h>

typedef unsigned int u32;
typedef unsigned long long u64;
typedef float v2f __attribute__((ext_vector_type(2)));
typedef float v4f __attribute__((ext_vector_type(4)));

// ---------------- workspace layout (bytes) ----------------
// conv phase: y + wT (wT aliases everything below, dead after k_conv1)
#define OFF_Y      0ull             // 8,388,608
#define OFF_WT     8388608ull       // 9,437,184 -> end 17,825,792
// post-conv phase (aliases wT region):
#define OFF_ZPART  8388608ull       // 4*45*4096*4 = 2,949,120
#define OFF_SCORES 11337728ull      // 147,456
#define OFF_DRAW   11485184ull      // 589,824
#define OFF_HIST   12075008ull      // 524,288
#define OFF_TOPV   12665344ull      // 24,576
#define OFF_BOXES  12714496ull      // 98,304
#define OFF_VW     12812800ull      // 1,024
#define OFF_MASK   12813824ull      // 6000*96*8 = 4,608,000 -> 17,421,824

#define NS     36864
#define PRE    6000
#define POST   300
#define SORTN  8192
#define MROW   96   // mask words per row (94 used)

// ====== K0: weight transpose gw[co][ci][k] -> wT[ci][k][co] (co fastest) ====
__global__ __launch_bounds__(256) void k_wtrans(const float* __restrict__ gw,
                                                float* __restrict__ wT) {
    int o = blockIdx.x * 256 + threadIdx.x;   // coalesced write
    if (o >= 512 * 512 * 9) return;
    int ci = o / 4608;
    int r = o - ci * 4608;
    int k = r >> 9;
    int co = r & 511;
    wT[o] = gw[co * 4608 + ci * 9 + k];
}

// ================= K1: 3x3 conv 512->512 + bias + relu (v6) =================
// grid 1024 = 16 co-blk x 64 h-blk -> 4 blocks/CU = 16 waves/CU.
// block 256 = 4 waves; tile 32 co x 1 row x 64 cols; wave = 8 co (pk pairs).
// rows=1 minimizes taps (9 floats/wave/ci); v_pk_fma over co-pairs via
// co-fastest wT layout; weights stream as broadcast float4 (vmcnt queue).
#define CI 16
#define XROW 66
#define CHUNK_ELEMS (CI * 3 * XROW)   // 3168
#define STAGE_IT 13
__global__ __launch_bounds__(256, 4) void k_conv1(const float* __restrict__ x,
                                                  const float* __restrict__ wT,
                                                  const float* __restrict__ gb,
                                                  float* __restrict__ y) {
    __shared__ float xs[CHUNK_ELEMS];   // 12,672 B
    const int t = threadIdx.x;
    const int tx = t & 63;
    const int wv = __builtin_amdgcn_readfirstlane(t >> 6);
    const int cob = (blockIdx.x & 15) << 5;
    const int h0 = blockIdx.x >> 4;
    const int co_base = cob + (wv << 3);   // 8 co per wave

    // staging map (constant across chunks; only ci-base shifts)
    int offs[STAGE_IT];
    u32 vmask = 0;
#pragma unroll
    for (int u = 0; u < STAGE_IT; ++u) {
        int idx = t + u * 256;
        offs[u] = 0;
        if (idx < CHUNK_ELEMS) {
            int ci = idx / (3 * XROW);
            int rem = idx - ci * (3 * XROW);
            int row = rem / XROW;
            int col = rem - row * XROW;
            int gr = h0 + row - 1, gc = col - 1;
            if ((unsigned)gr < 64u && (unsigned)gc < 64u) {
                offs[u] = ci * 4096 + (gr << 6) + gc;
                vmask |= 1u << u;
            }
        }
    }

    v2f acc2[4];
#pragma unroll
    for (int j = 0; j < 4; ++j) acc2[j] = (v2f){0.f, 0.f};

    float st[STAGE_IT];
#pragma unroll
    for (int u = 0; u < STAGE_IT; ++u)
        st[u] = (vmask >> u & 1) ? x[offs[u]] : 0.f;

#pragma unroll 1
    for (int cc = 0; cc < 32; ++cc) {
        if (cc) __syncthreads();
#pragma unroll
        for (int u = 0; u < STAGE_IT; ++u) {
            int idx = t + u * 256;
            if (idx < CHUNK_ELEMS) xs[idx] = st[u];
        }
        __syncthreads();
        if (cc + 1 < 32) {
            const float* xsrc = x + (cc + 1) * CI * 4096;
#pragma unroll
            for (int u = 0; u < STAGE_IT; ++u)
                st[u] = (vmask >> u & 1) ? xsrc[offs[u]] : 0.f;
        }

        const int cig0 = cc * CI;
#pragma unroll 2
        for (int ci = 0; ci < CI; ++ci) {
            float xr[9];
            {
                const float* xp = xs + ci * (3 * XROW) + tx;
#pragma unroll
                for (int r = 0; r < 3; ++r) {
                    xr[r * 3 + 0] = xp[r * XROW + 0];
                    xr[r * 3 + 1] = xp[r * XROW + 1];
                    xr[r * 3 + 2] = xp[r * XROW + 2];
                }
            }
            // wT[ci][k][co]: wave's 8 co contiguous -> 2 float4 per k
            const float* wk = wT + (size_t)(cig0 + ci) * 4608 + co_base;
#pragma unroll
            for (int k = 0; k < 9; ++k) {
                v4f wa = *(const v4f*)(wk + k * 512);
                v4f wb = *(const v4f*)(wk + k * 512 + 4);
                float xv = xr[k];
                v2f xp2 = {xv, xv};
                acc2[0] = __builtin_elementwise_fma(__builtin_shufflevector(wa, wa, 0, 1), xp2, acc2[0]);
                acc2[1] = __builtin_elementwise_fma(__builtin_shufflevector(wa, wa, 2, 3), xp2, acc2[1]);
                acc2[2] = __builtin_elementwise_fma(__builtin_shufflevector(wb, wb, 0, 1), xp2, acc2[2]);
                acc2[3] = __builtin_elementwise_fma(__builtin_shufflevector(wb, wb, 2, 3), xp2, acc2[3]);
            }
        }
    }

#pragma unroll
    for (int j = 0; j < 4; ++j) {
        int co0 = co_base + 2 * j;
        float v0 = acc2[j].x + gb[co0];
        float v1 = acc2[j].y + gb[co0 + 1];
        v0 = v0 > 0.f ? v0 : 0.f;
        v1 = v1 > 0.f ? v1 : 0.f;
        y[co0 * 4096 + (h0 << 6) + tx] = v0;
        y[(co0 + 1) * 4096 + (h0 << 6) + tx] = v1;
    }
}

// ================= K2a: 1x1 heads, partial over ci quarters =================
// grid 256 = 64 px-chunks x 4 ci-quarters; block 256 = 64 px x 4 wave-groups.
// Also zeroes the 512 KB histogram (512 dwords per block) — runs after conv
// consumed wT (hist aliases wT region), before k_hreduce uses it.
__global__ __launch_bounds__(256) void k_heads_part(const float* __restrict__ y,
                                                    const float* __restrict__ cw,
                                                    const float* __restrict__ bw,
                                                    float* __restrict__ zpart,
                                                    u32* __restrict__ hist) {
    __shared__ __align__(16) float ys[64][132];  // 33,792 B
    const int t = threadIdx.x;
    // hist zero: 256 blocks x 512 dwords
    {
        int hb = blockIdx.x << 9;
        hist[hb + t] = 0u;
        hist[hb + 256 + t] = 0u;
    }
    const int px = t & 63;
    const int gu = __builtin_amdgcn_readfirstlane(t >> 6);
    const int px0 = (blockIdx.x & 63) << 6;
    const int q = blockIdx.x >> 6;
    const int cib = q << 7;
    const int nch = (gu == 0) ? 12 : 11;

    const float* wrow[12];
#pragma unroll
    for (int j = 0; j < 12; ++j) {
        int ch = gu + 4 * j;
        if (ch < 9) wrow[j] = cw + ch * 512;
        else if (ch < 45) wrow[j] = bw + (ch - 9) * 512;
        else wrow[j] = cw;
    }
    float acc[12];
#pragma unroll
    for (int j = 0; j < 12; ++j) acc[j] = 0.f;

    for (int idx = t; idx < 128 * 64; idx += 256) {
        int ci = idx >> 6;
        int pp = idx & 63;
        ys[pp][ci] = y[(cib + ci) * 4096 + px0 + pp];
    }
    __syncthreads();

#pragma unroll 1
    for (int cq = 0; cq < 32; ++cq) {
        float4 yv = *(const float4*)&ys[px][cq << 2];
        float4 wv[12];
#pragma unroll
        for (int j = 0; j < 12; ++j)
            if (j < nch) wv[j] = *(const float4*)(wrow[j] + cib + (cq << 2));
#pragma unroll
        for (int j = 0; j < 12; ++j)
            if (j < nch)
                acc[j] += wv[j].x * yv.x + wv[j].y * yv.y + wv[j].z * yv.z + wv[j].w * yv.w;
    }
    for (int j = 0; j < nch; ++j) {
        int ch = gu + 4 * j;
        zpart[((q * 45 + ch) << 12) + px0 + px] = acc[j];
    }
}

// ================= K2b: reduce partials + bias + sigmoid + hist =============
__global__ __launch_bounds__(256) void k_hreduce(const float* __restrict__ zpart,
                                                 const float* __restrict__ cb,
                                                 const float* __restrict__ bb,
                                                 float* __restrict__ scores,
                                                 float* __restrict__ draw,
                                                 u32* __restrict__ hist) {
    int i = blockIdx.x * 256 + threadIdx.x;
    if (i >= 45 * 4096) return;
    int ch = i >> 12;
    int sp = i & 4095;
    float z = zpart[((0 * 45 + ch) << 12) + sp] + zpart[((1 * 45 + ch) << 12) + sp] +
              zpart[((2 * 45 + ch) << 12) + sp] + zpart[((3 * 45 + ch) << 12) + sp];
    if (ch < 9) {
        z += cb[ch];
        float s = 1.f / (1.f + expf(-z));
        scores[(ch << 12) + sp] = s;
        u32 sb = __float_as_uint(s);
        atomicAdd(&hist[sb >> 13], 1u);
    } else {
        z += bb[ch - 9];
        draw[((ch - 9) << 12) + sp] = z;
    }
}

// ======== K3: fused select = hist-scan + compact + bitonic sort + decode ====
__global__ __launch_bounds__(1024) void k_select(const u32* __restrict__ hist,
                                                 const float* __restrict__ scores,
                                                 const float* __restrict__ draw,
                                                 const float* __restrict__ anchors,
                                                 const int* __restrict__ ishape,
                                                 float* __restrict__ boxes,
                                                 float* __restrict__ topv,
                                                 u64* __restrict__ vw) {
    __shared__ u32 csum[1024];
    __shared__ u32 suf[1024];
    __shared__ u64 sk[SORTN];   // 64 KB
    __shared__ int sel_s, cnt_s;
    const int t = threadIdx.x;

    u32 s = 0;
    const u32* hp = hist + t * 128;
    for (int i = 0; i < 128; ++i) s += hp[i];
    csum[t] = s;
    suf[t] = s;
    if (t == 0) cnt_s = 0;
    __syncthreads();
    for (int off = 1; off < 1024; off <<= 1) {
        u32 v = suf[t] + ((t + off < 1024) ? suf[t + off] : 0u);
        __syncthreads();
        suf[t] = v;
        __syncthreads();
    }
    u32 above = suf[t] - csum[t];
    if (above < (u32)PRE && suf[t] >= (u32)PRE) {
        u32 run = above;
        int bstar = t * 128;
        u32 found = 0;
        for (int b2 = 127; b2 >= 0; --b2) {
            u32 c = hp[b2];
            if (!found && run + c >= (u32)PRE) { bstar = t * 128 + b2; found = 1; }
            if (!found) run += c;
        }
        sel_s = bstar;
    }
    for (int i = t; i < SORTN; i += 1024) sk[i] = 0;
    __syncthreads();

    const int sel = sel_s;
    for (int i = t; i < NS; i += 1024) {
        u32 sb = __float_as_uint(scores[i]);
        if ((int)(sb >> 13) >= sel) {
            int p = atomicAdd(&cnt_s, 1);
            if (p < SORTN) sk[p] = ((u64)sb << 32) | (u32)(~i);
        }
    }
    __syncthreads();

    const int base = t << 3;
    u64 a[8];
    {
#pragma unroll
        for (int u = 0; u < 8; ++u) a[u] = sk[base + u];
#pragma unroll
        for (int k = 2; k <= 8; k <<= 1) {
#pragma unroll
            for (int j = k >> 1; j > 0; j >>= 1) {
#pragma unroll
                for (int u = 0; u < 8; ++u) {
                    if ((u & j) == 0) {
                        int l = u | j;
                        bool up = (((base + u) & k) == 0);
                        u64 x0 = a[u], x1 = a[l];
                        if (up ? (x0 < x1) : (x0 > x1)) { a[u] = x1; a[l] = x0; }
                    }
                }
            }
        }
#pragma unroll
        for (int u = 0; u < 8; ++u) sk[base + u] = a[u];
        __syncthreads();
    }
    for (int k = 16; k <= SORTN; k <<= 1) {
        for (int j = k >> 1; j >= 8; j >>= 1) {
#pragma unroll
            for (int s2 = 0; s2 < 4; ++s2) {
                int pidx = t + (s2 << 10);
                int i = ((pidx & ~(j - 1)) << 1) | (pidx & (j - 1));
                int l = i | j;
                u64 x0 = sk[i], x1 = sk[l];
                bool up = ((i & k) == 0);
                if (up ? (x0 < x1) : (x0 > x1)) { sk[i] = x1; sk[l] = x0; }
            }
            __syncthreads();
        }
#pragma unroll
        for (int u = 0; u < 8; ++u) a[u] = sk[base + u];
        {
            bool up = ((base & k) == 0);
#pragma unroll
            for (int j = 4; j > 0; j >>= 1) {
#pragma unroll
                for (int u = 0; u < 8; ++u) {
                    if ((u & j) == 0) {
                        int l = u | j;
                        u64 x0 = a[u], x1 = a[l];
                        if (up ? (x0 < x1) : (x0 > x1)) { a[u] = x1; a[l] = x0; }
                    }
                }
            }
        }
#pragma unroll
        for (int u = 0; u < 8; ++u) sk[base + u] = a[u];
        __syncthreads();
    }

    const float wimg = (float)ishape[1], himg = (float)ishape[0];
#pragma unroll 1
    for (int s2 = 0; s2 < 6; ++s2) {
        int r = (s2 << 10) + t;
        bool valid = false;
        if (r < PRE) {
            u64 key = sk[r];
            u32 sb = (u32)(key >> 32);
            int i = (int)(~(u32)key);
            topv[r] = __uint_as_float(sb);
            int c = i >> 10;
            int t4 = i & 1023;
            float4 d4 = *(const float4*)(draw + c * 4096 + (t4 << 2));
            float4 a4 = *(const float4*)(anchors + i * 4);
            float aw = a4.z - a4.x, ah = a4.w - a4.y;
            float ax = a4.x + 0.5f * aw, ay = a4.y + 0.5f * ah;
            const float CLIPV = (float)4.135166556742356;
            float dw = fminf(d4.z, CLIPV);
            float dh = fminf(d4.w, CLIPV);
            float px = d4.x * aw + ax, py = d4.y * ah + ay;
            float pw = expf(dw) * aw, ph = expf(dh) * ah;
            float x1 = fminf(fmaxf(px - 0.5f * pw, 0.f), wimg);
            float y1 = fminf(fmaxf(py - 0.5f * ph, 0.f), himg);
            float x2 = fminf(fmaxf(px + 0.5f * pw, 0.f), wimg);
            float y2 = fminf(fmaxf(py + 0.5f * ph, 0.f), himg);
            valid = (x2 - x1 >= 16.f) && (y2 - y1 >= 16.f);
            *(float4*)(boxes + r * 4) = make_float4(x1, y1, x2, y2);
        }
        u64 bm = __ballot(valid);
        if ((t & 63) == 0) vw[(s2 << 4) + (t >> 6)] = bm;
    }
}

// ================= K4: suppression bitmask (iou > 0.7, j > row) =============
__global__ __launch_bounds__(256) void k_mask(const float* __restrict__ boxes,
                                              u64* __restrict__ mask) {
    __shared__ float4 cbx[16 * 65];
    const int t = threadIdx.x;
    const int r0 = blockIdx.x << 4;
    const int row = r0 + (t >> 4);
    const int wloc = t & 15;
    float4 rb = *(const float4*)(boxes + row * 4);
    float area_a = (rb.z - rb.x) * (rb.w - rb.y);
    for (int chunk = 0; chunk < 6; ++chunk) {
        int j0c = chunk << 10;
        for (int idx = t; idx < 1024; idx += 256) {
            int j = j0c + idx;
            float4 v = make_float4(0.f, 0.f, 0.f, 0.f);
            if (j < PRE) v = *(const float4*)(boxes + j * 4);
            cbx[(idx >> 6) * 65 + (idx & 63)] = v;
        }
        __syncthreads();
        u64 bits = 0;
        const float4* cbr = cbx + wloc * 65;
        for (int b = 0; b < 64; ++b) {
            int j = j0c + (wloc << 6) + b;
            float4 ob = cbr[b];
            float area_b = (ob.z - ob.x) * (ob.w - ob.y);
            float ltx = fmaxf(rb.x, ob.x), lty = fmaxf(rb.y, ob.y);
            float rbx = fminf(rb.z, ob.z), rby = fminf(rb.w, ob.w);
            float wx = fmaxf(rbx - ltx, 0.f), wy = fmaxf(rby - lty, 0.f);
            float inter = wx * wy;
            float uni = area_a + area_b - inter;
            float iou = (uni > 0.f) ? (inter / uni) : 0.f;
            if (iou > 0.7f && j > row && j < PRE) bits |= (1ull << b);
        }
        mask[(size_t)row * MROW + (chunk << 4) + wloc] = bits;
        __syncthreads();
    }
}

// ======== K5: fused NMS (serial greedy, batch-16 prefetch) + output write ===
__global__ __launch_bounds__(320) void k_nms_out(const u64* __restrict__ mask,
                                                 const u64* __restrict__ vw,
                                                 const float* __restrict__ boxes,
                                                 const float* __restrict__ topv,
                                                 float* __restrict__ out) {
    __shared__ u64 rem[MROW];
    __shared__ u64 rows16[16][MROW];   // 12,288 B
    __shared__ u64 kws[MROW];
    __shared__ int keepl[POST];
    const int tid = threadIdx.x;
    for (int i = tid; i < MROW; i += 320) { rem[i] = 0ull; kws[i] = 0ull; }
    __syncthreads();
    int kc = 0;
    bool done = false;
    for (int w = 0; w < 94 && !done; ++w) {
        u64 aw = vw[w] & ~rem[w];
        u64 kwbits = 0;
        while (aw != 0ull && !done) {
            int bq[16];
            u64 tmp = aw;
#pragma unroll
            for (int q2 = 0; q2 < 16; ++q2) {
                bq[q2] = tmp ? __builtin_ctzll(tmp) : 64;
                tmp &= tmp - 1;
            }
#pragma unroll
            for (int u = 0; u < 5; ++u) {
                int i = tid + u * 320;
                if (i < 16 * MROW) {
                    int q2 = i / MROW;
                    int ww = i - q2 * MROW;
                    if (bq[q2] < 64)
                        rows16[q2][ww] = mask[(size_t)((w << 6) + bq[q2]) * MROW + ww];
                }
            }
            __syncthreads();
            for (int q2 = 0; q2 < 16; ++q2) {
                int b = bq[q2];
                if (b >= 64) break;
                if (!((aw >> b) & 1ull)) continue;
                if (tid == 0) keepl[kc] = (w << 6) + b;
                kc++;
                kwbits |= (1ull << b);
                if (kc >= POST) { done = true; break; }
                if (tid < MROW) rem[tid] |= rows16[q2][tid];
                aw &= ~rows16[q2][w];
                aw &= ~(1ull << b);
            }
            __syncthreads();
        }
        if (tid == 0) kws[w] = kwbits;
        __syncthreads();
    }
    __syncthreads();

    int j = tid;
    if (j >= POST) return;
    int kc2 = kc;
    int r;
    float sc;
    if (j < kc2) {
        r = keepl[j];
        sc = topv[r];
    } else {
        int target = j - kc2;
        r = PRE - 1;
        int cum = 0;
        for (int w = 0; w < 94; ++w) {
            u64 kb = kws[w];
            int nvalid = (w < 93) ? 64 : 48;
            u64 vmask2 = (nvalid == 64) ? ~0ull : ((1ull << nvalid) - 1ull);
            u64 nk = (~kb) & vmask2;
            int c = __popcll(nk);
            if (cum + c > target) {
                int need = target - cum;
                u64 m = nk;
                for (int q = 0; q < need; ++q) m &= (m - 1);
                r = (w << 6) + __builtin_ctzll(m);
                break;
            }
            cum += c;
        }
        sc = -1.0f;
    }
    out[j * 4 + 0] = boxes[r * 4 + 0];
    out[j * 4 + 1] = boxes[r * 4 + 1];
    out[j * 4 + 2] = boxes[r * 4 + 2];
    out[j * 4 + 3] = boxes[r * 4 + 3];
    out[1200 + j] = sc;
}

extern "C" void kernel_launch(void* const* d_in, const int* in_sizes, int n_in,
                              void* d_out, int out_size, void* d_ws, size_t ws_size,
                              hipStream_t stream) {
    const float* x = (const float*)d_in[0];
    const float* anchors = (const float*)d_in[1];
    const int* ishape = (const int*)d_in[2];
    const float* c1w = (const float*)d_in[3];
    const float* c1b = (const float*)d_in[4];
    const float* clw = (const float*)d_in[5];
    const float* clb = (const float*)d_in[6];
    const float* bxw = (const float*)d_in[7];
    const float* bxb = (const float*)d_in[8];

    char* ws = (char*)d_ws;
    float* y      = (float*)(ws + OFF_Y);
    float* wT     = (float*)(ws + OFF_WT);
    float* zpart  = (float*)(ws + OFF_ZPART);
    float* scores = (float*)(ws + OFF_SCORES);
    float* draw   = (float*)(ws + OFF_DRAW);
    u32*   hist   = (u32*)(ws + OFF_HIST);
    float* topv   = (float*)(ws + OFF_TOPV);
    float* boxes  = (float*)(ws + OFF_BOXES);
    u64*   vw     = (u64*)(ws + OFF_VW);
    u64*   mask   = (u64*)(ws + OFF_MASK);

    k_wtrans<<<(512 * 512 * 9 + 255) / 256, 256, 0, stream>>>(c1w, wT);
    k_conv1<<<1024, 256, 0, stream>>>(x, wT, c1b, y);
    k_heads_part<<<256, 256, 0, stream>>>(y, clw, bxw, zpart, hist);
    k_hreduce<<<(45 * 4096 + 255) / 256, 256, 0, stream>>>(zpart, clb, bxb, scores, draw, hist);
    k_select<<<1, 1024, 0, stream>>>(hist, scores, draw, anchors, ishape, boxes, topv, vw);
    k_mask<<<PRE / 16, 256, 0, stream>>>(boxes, mask);
    k_nms_out<<<1, 320, 0, stream>>>(mask, vw, boxes, topv, (float*)d_out);
}